// Round 7
// baseline (328.183 us; speedup 1.0000x reference)
//
#include <hip/hip_runtime.h>
#include <hip/hip_bf16.h>

// Problem: B=8, C=256, H=W=96, c8=32, pool sizes {1,3,5,7,14} -> 280 positions.
// Restructured: out[b,o] = sum_k aff[b,o,k] * conv3x3(x_1[b], con[k])
//               psp(wq@x+bq) = wq@psp(x)+bq  (pool rows sum to 1)
// yconv as implicit-GEMM bf16 MFMA staging DIRECTLY from f32 x1 (the old
// x2bf channel-last pass is folded into staging); mix as MFMA GEMM over K=32
// with kc summed in the accumulator (Yp [kc][b][px][k], aff bf16 [b][o][k]).
// pool: h-bin first directly from global (coalesced column reads), then
// w-prefix + differences. Ph@X@Pw^T commutes.

#define B 8
#define C 256
#define C8 32
#define H 96
#define W 96
#define HW 9216
#define NPOS 280
#define NWBIN 30
#define RPS 108   // colp stride (floats)
#define OTS 68    // mix epilogue LDS stride (floats): 2-way banks on write+read

typedef __attribute__((ext_vector_type(8))) short short8;
typedef __attribute__((ext_vector_type(4))) float float4v;
typedef __attribute__((ext_vector_type(4))) unsigned short ushort4v;

static __device__ __forceinline__ unsigned short f2bf(float f) {
    unsigned u = __float_as_uint(f);
    unsigned r = (u + 0x7FFF + ((u >> 16) & 1)) >> 16;   // RNE
    return (unsigned short)r;
}
static __device__ __forceinline__ float bf2f(unsigned short h) {
    unsigned u = ((unsigned)h) << 16;
    return __uint_as_float(u);
}

// Accumulate one half-column (48 rows starting at compile-time H0, column w)
// into the 30 h-bins, reading DIRECTLY from global (coalesced across lanes).
template<int H0>
static __device__ __forceinline__ void accum_half_col(const float* __restrict__ col0,
                                                      float acc[NWBIN]) {
    const int SC[5]   = {1, 3, 5, 7, 14};
    const int WOFF[5] = {0, 1, 4, 9, 16};
    #pragma unroll
    for (int k = 0; k < NWBIN; ++k) acc[k] = 0.f;
    #pragma unroll
    for (int g = 0; g < 4; ++g) {
        float v[12];
        #pragma unroll
        for (int q = 0; q < 12; ++q) v[q] = col0[(size_t)(H0 + g * 12 + q) * 96];
        #pragma unroll
        for (int q = 0; q < 12; ++q) {
            const int h = H0 + g * 12 + q;
            #pragma unroll
            for (int si = 0; si < 5; ++si) {
                #pragma unroll
                for (int j = 0; j < SC[si]; ++j) {
                    const int st = (j * 96) / SC[si];
                    const int en = (96 * (j + 1) + SC[si] - 1) / SC[si];
                    if (h >= st && h < en) acc[WOFF[si] + j] += v[q];
                }
            }
        }
    }
}

// ---------------- pooling: [B,C,96,96] -> [B,C,280] for both x_1 and x ----
__global__ __launch_bounds__(256) void pool_kernel(const float* __restrict__ x1,
                                                   const float* __restrict__ x,
                                                   float* __restrict__ px1,
                                                   float* __restrict__ px) {
    __shared__ __align__(16) float colp[NWBIN * RPS];   // 12960 B
    const int bi = blockIdx.x;           // 0..4095
    const int which = bi >> 11;          // 0: x_1, 1: x
    const int bc = bi & 2047;
    const float* __restrict__ src = (which ? x : x1) + (size_t)bc * HW;
    float* __restrict__ dst = (which ? px : px1) + (size_t)bc * NPOS;
    const int tid = threadIdx.x;

    const int SC[5]   = {1, 3, 5, 7, 14};
    const int WOFF[5] = {0, 1, 4, 9, 16};
    const int POFF[5] = {0, 1, 10, 35, 84};

    // phase 1: h-bin accumulation into registers, straight from global
    float acc[NWBIN];
    if (tid < 96) {                              // column w=tid, h in [0,48)
        accum_half_col<0>(src + tid, acc);
    } else if (tid >= 128 && tid < 224) {        // column, h in [48,96)
        accum_half_col<48>(src + (tid - 128), acc);
    }

    // upper half publishes
    if (tid >= 128 && tid < 224) {
        const int w1 = tid - 128;
        #pragma unroll
        for (int si = 0; si < 5; ++si) {
            #pragma unroll
            for (int i = 0; i < SC[si]; ++i)
                colp[(WOFF[si] + i) * RPS + w1] = acc[WOFF[si] + i];
        }
    }
    __syncthreads();
    // combine halves + scale by 1/(h-bin width)
    if (tid < 96) {
        #pragma unroll
        for (int si = 0; si < 5; ++si) {
            #pragma unroll
            for (int i = 0; i < SC[si]; ++i) {
                const int st = (i * 96) / SC[si];
                const int en = (96 * (i + 1) + SC[si] - 1) / SC[si];
                const float inv = 1.0f / (float)(en - st);
                const int bin = WOFF[si] + i;
                colp[bin * RPS + tid] = (acc[bin] + colp[bin * RPS + tid]) * inv;
            }
        }
    }
    __syncthreads();

    // phase C: in-place prefix sum over w per h-bin (30 threads, b128)
    if (tid < NWBIN) {
        float run = 0.f;
        #pragma unroll
        for (int c = 0; c < 24; ++c) {
            float4 v = *(const float4*)&colp[tid * RPS + 4 * c];
            v.x += run; v.y += v.x; v.z += v.y; v.w += v.z;
            run = v.w;
            *(float4*)&colp[tid * RPS + 4 * c] = v;
        }
    }
    __syncthreads();

    // phase D: 280 outputs, each = w-prefix difference * 1/(w-bin width)
    for (int p = tid; p < NPOS; p += 256) {
        int si;
        if (p < 1) si = 0; else if (p < 10) si = 1; else if (p < 35) si = 2;
        else if (p < 84) si = 3; else si = 4;
        int s = SC[si];
        int loc = p - POFF[si];
        int i = loc / s;            // h-bin index
        int j = loc - i * s;        // w-bin index
        int st = (j * 96) / s;
        int en = (96 * (j + 1) + s - 1) / s;
        int binrow = WOFF[si] + i;
        float hi = colp[binrow * RPS + (en - 1)];
        float lo = (st > 0) ? colp[binrow * RPS + (st - 1)] : 0.f;
        dst[p] = (hi - lo) * (1.0f / (float)(en - st));
    }
}

// ---------------- proj: PQ = wq@px1+bq [B,256,280]; PK = wk@px+bk [B,32,280]
__global__ __launch_bounds__(320) void proj_kernel(const float* __restrict__ px1,
                                                   const float* __restrict__ px,
                                                   const float* __restrict__ wq,
                                                   const float* __restrict__ bq,
                                                   const float* __restrict__ wk,
                                                   const float* __restrict__ bk,
                                                   float* __restrict__ PQ,
                                                   float* __restrict__ PK) {
    const int bi = blockIdx.x;   // B * 72
    const int b = bi / 72;
    const int r = bi % 72;
    const int tid = threadIdx.x;
    const float* src;
    const float* wm;
    const float* bias;
    float* dst;
    int o0;
    if (r < 64) {
        o0 = r * 4;
        src = px1 + (size_t)b * C * NPOS;
        wm = wq; bias = bq;
        dst = PQ + ((size_t)b * C + o0) * NPOS;
    } else {
        o0 = (r - 64) * 4;
        src = px + (size_t)b * C * NPOS;
        wm = wk; bias = bk;
        dst = PK + ((size_t)b * C8 + o0) * NPOS;
    }
    if (tid >= NPOS) return;
    float a0 = 0.f, a1 = 0.f, a2 = 0.f, a3 = 0.f;
    for (int c = 0; c < C; ++c) {
        float xv = src[c * NPOS + tid];
        a0 += wm[(o0 + 0) * C + c] * xv;
        a1 += wm[(o0 + 1) * C + c] * xv;
        a2 += wm[(o0 + 2) * C + c] * xv;
        a3 += wm[(o0 + 3) * C + c] * xv;
    }
    dst[0 * NPOS + tid] = a0 + bias[o0 + 0];
    dst[1 * NPOS + tid] = a1 + bias[o0 + 1];
    dst[2 * NPOS + tid] = a2 + bias[o0 + 2];
    dst[3 * NPOS + tid] = a3 + bias[o0 + 3];
}

// ---------------- aff[b,o,k] = sigmoid(PQ[b,o,:] . PK[b,k,:]) -> bf16 ------
__global__ __launch_bounds__(256) void aff_kernel(const float* __restrict__ PQ,
                                                  const float* __restrict__ PK,
                                                  unsigned short* __restrict__ affb) {
    __shared__ float pk[NPOS];
    const int b = blockIdx.x >> 5;
    const int k = blockIdx.x & 31;
    const int tid = threadIdx.x;
    const float* __restrict__ pkr = PK + ((size_t)b * C8 + k) * NPOS;
    if (tid < 256) pk[tid] = pkr[tid];
    if (tid < NPOS - 256) pk[tid + 256] = pkr[tid + 256];
    __syncthreads();
    const float4* __restrict__ q4 = (const float4*)(PQ + ((size_t)b * C + tid) * NPOS);
    const float4* __restrict__ p4 = (const float4*)pk;
    float acc = 0.f;
    #pragma unroll 10
    for (int i = 0; i < NPOS / 4; ++i) {
        float4 a = q4[i];
        float4 c = p4[i];
        acc += a.x * c.x + a.y * c.y + a.z * c.z + a.w * c.w;
    }
    float s = 1.0f / (1.0f + __expf(-acc));
    affb[((size_t)b * C + tid) * C8 + k] = f2bf(s);
}

// ---------------- prep: con[k,c,3,3] -> Aswz in MFMA A-fragment order ------
__global__ __launch_bounds__(256) void aswz_kernel(const float* __restrict__ con,
                                                   unsigned short* __restrict__ aswz) {
    int idx = blockIdx.x * 256 + threadIdx.x;   // 72*2*64*8 = 73728
    if (idx >= 73728) return;
    int j = idx & 7;
    int lane = (idx >> 3) & 63;
    int mt = (idx >> 9) & 1;
    int s = idx >> 10;          // 0..71
    int pos = s >> 3;
    int cg = s & 7;
    int m = lane & 15, quad = lane >> 4;
    int ko = mt * 16 + m;
    int c = cg * 32 + quad * 8 + j;
    int dy = pos / 3, dx = pos - dy * 3;
    float v = con[((ko * C + c) * 3 + dy) * 3 + dx];
    aswz[idx] = f2bf(v);
}

// ---------------- Y = W @ im2col(x1) via MFMA, K split over 4 blocks -------
// Stages DIRECTLY from f32 x1 (channel-major): scalar coalesced loads +
// f2bf + b16 LDS writes do the transpose in-flight (x2bf pass eliminated).
// Output layout: Yp[kc][b][px][k] bf16 (k contiguous) for MFMA-ready mix.
__global__ __launch_bounds__(256) void yconv_mfma(const float* __restrict__ x1,
                                                  const unsigned short* __restrict__ aswz,
                                                  unsigned short* __restrict__ Yp) {
    __shared__ unsigned short xsl[10 * 50 * 40];   // [pix][ch pad 40] = 40000 B
    const int bi = blockIdx.x;
    const int kc = bi & 3;
    const int rest = bi >> 2;          // 0..191
    const int tilex = rest & 1;
    const int tiley = (rest >> 1) % 12;
    const int b = rest / 24;
    const int tid = threadIdx.x;
    const int wid = tid >> 6;
    const int lane = tid & 63;
    const int n = lane & 15, quad = lane >> 4;

    float4v acc[2][6];
    #pragma unroll
    for (int mt = 0; mt < 2; ++mt)
        #pragma unroll
        for (int t = 0; t < 6; ++t)
            acc[mt][t] = (float4v){0.f, 0.f, 0.f, 0.f};

    int baseb[6];
    #pragma unroll
    for (int t = 0; t < 6; ++t) {
        int tt = wid * 6 + t;
        int rt = tt / 3;
        int xb = (tt % 3) * 16;
        baseb[t] = (rt * 50 + xb + n) * 40 + quad * 8;
    }

    for (int ci = 0; ci < 2; ++ci) {
        const int cg = kc * 2 + ci;
        __syncthreads();
        // stage X slab from f32 x1: 32 ch x 500 px, coalesced scalar loads,
        // convert + transpose into [pix][ch] bf16 LDS
        const float* __restrict__ xsrc = x1 + ((size_t)b * C + cg * 32) * HW;
        #pragma unroll 4
        for (int it = 0; it < 64; ++it) {
            int task = it * 256 + tid;
            int ch = task >> 9;          // 0..31
            int pix = task & 511;        // 0..511 (>=500 skipped)
            int r = pix / 50;
            int col = pix - r * 50;
            int gy = tiley * 8 + r - 1;
            int gx = tilex * 48 + col - 1;
            if (pix < 500) {
                float v = 0.f;
                if ((unsigned)gy < 96u && (unsigned)gx < 96u)
                    v = xsrc[(size_t)ch * HW + gy * 96 + gx];
                xsl[pix * 40 + ch] = f2bf(v);
            }
        }
        // A-fragments straight from global (L2-hot, 18 x 16B per lane)
        short8 af[9][2];
        #pragma unroll
        for (int pos = 0; pos < 9; ++pos)
            #pragma unroll
            for (int mt = 0; mt < 2; ++mt)
                af[pos][mt] = *(const short8*)&aswz[((((pos * 8 + cg) * 2) + mt) * 64 + lane) * 8];
        __syncthreads();

        #pragma unroll
        for (int pos = 0; pos < 9; ++pos) {
            const int dy = pos / 3, dx = pos - (pos / 3) * 3;
            const int d = (dy * 50 + dx) * 40;
            #pragma unroll
            for (int t = 0; t < 6; ++t) {
                short8 bf = *(const short8*)&xsl[baseb[t] + d];
                acc[0][t] = __builtin_amdgcn_mfma_f32_16x16x32_bf16(af[pos][0], bf, acc[0][t], 0, 0, 0);
                acc[1][t] = __builtin_amdgcn_mfma_f32_16x16x32_bf16(af[pos][1], bf, acc[1][t], 0, 0, 0);
            }
        }
    }

    // store partial: D col=lane&15 -> pixel n, row=quad*4+reg -> k_out.
    // Layout [kc][b][px][k]: 4 consecutive regs = 4 consecutive k -> 8B store.
    #pragma unroll
    for (int mt = 0; mt < 2; ++mt) {
        #pragma unroll
        for (int t = 0; t < 6; ++t) {
            int tt = wid * 6 + t;
            int rt = tt / 3;
            int xb = (tt % 3) * 16;
            int gy = tiley * 8 + rt;
            int gx = tilex * 48 + xb + n;
            ushort4v v;
            #pragma unroll
            for (int reg = 0; reg < 4; ++reg) v[reg] = f2bf(acc[mt][t][reg]);
            *(ushort4v*)&Yp[((((size_t)kc * B + b) * HW + gy * 96 + gx)) * C8 + mt * 16 + quad * 4] = v;
        }
    }
}

// ---------------- mix: out[b,o,px] = sum_k aff[b,o,k] * sum_kc Yp ----------
__global__ __launch_bounds__(256) void mix_kernel(const unsigned short* __restrict__ Yp,
                                                  const unsigned short* __restrict__ affb,
                                                  float* __restrict__ out) {
    __shared__ float ot[128 * OTS];   // 34816 B
    const int bi = blockIdx.x;   // 1152
    const int b = bi / 144;
    const int pg = bi % 144;
    const int wid = threadIdx.x >> 6;
    const int lane = threadIdx.x & 63;
    const int n = lane & 15, quad = lane >> 4;
    const int px0 = pg * 64 + wid * 16;   // this wave's 16-px column tile

    // B-frags, one per kc: B[k=quad*8+j][n(px)] ; wave reads 1KB contiguous
    short8 y0 = *(const short8*)&Yp[(((size_t)0 * B + b) * HW + px0 + n) * C8 + quad * 8];
    short8 y1 = *(const short8*)&Yp[(((size_t)1 * B + b) * HW + px0 + n) * C8 + quad * 8];
    short8 y2 = *(const short8*)&Yp[(((size_t)2 * B + b) * HW + px0 + n) * C8 + quad * 8];
    short8 y3 = *(const short8*)&Yp[(((size_t)3 * B + b) * HW + px0 + n) * C8 + quad * 8];

    float4v acc[16];
    #pragma unroll
    for (int mt = 0; mt < 16; ++mt) acc[mt] = (float4v){0.f, 0.f, 0.f, 0.f};

    #pragma unroll
    for (int mt = 0; mt < 16; ++mt) {
        // A-frag: A[m=lane&15][k=quad*8+j] = aff[b][mt*16+m][k]  (L2-hot)
        const short8 a = *(const short8*)&affb[((size_t)b * C + mt * 16 + n) * C8 + quad * 8];
        acc[mt] = __builtin_amdgcn_mfma_f32_16x16x32_bf16(a, y0, acc[mt], 0, 0, 0);
        acc[mt] = __builtin_amdgcn_mfma_f32_16x16x32_bf16(a, y1, acc[mt], 0, 0, 0);
        acc[mt] = __builtin_amdgcn_mfma_f32_16x16x32_bf16(a, y2, acc[mt], 0, 0, 0);
        acc[mt] = __builtin_amdgcn_mfma_f32_16x16x32_bf16(a, y3, acc[mt], 0, 0, 0);
    }

    // epilogue: two halves of 128 o-rows through LDS -> contiguous 256B stores
    #pragma unroll
    for (int half = 0; half < 2; ++half) {
        __syncthreads();
        #pragma unroll
        for (int mt = 0; mt < 8; ++mt) {
            #pragma unroll
            for (int reg = 0; reg < 4; ++reg) {
                // D: col=lane&15 -> px, row=quad*4+reg -> o   (2-way banks, free)
                ot[(mt * 16 + quad * 4 + reg) * OTS + wid * 16 + n] = acc[half * 8 + mt][reg];
            }
        }
        __syncthreads();
        #pragma unroll
        for (int i = 0; i < 32; ++i) {
            int o = wid * 32 + i;          // local o within half
            out[((size_t)b * C + half * 128 + o) * HW + pg * 64 + lane] = ot[o * OTS + lane];
        }
    }
}

extern "C" void kernel_launch(void* const* d_in, const int* in_sizes, int n_in,
                              void* d_out, int out_size, void* d_ws, size_t ws_size,
                              hipStream_t stream) {
    const float* x1  = (const float*)d_in[0];
    const float* x   = (const float*)d_in[1];
    const float* wq  = (const float*)d_in[2];
    const float* bq  = (const float*)d_in[3];
    const float* wk  = (const float*)d_in[4];
    const float* bk  = (const float*)d_in[5];
    const float* con = (const float*)d_in[6];
    float* out = (float*)d_out;

    float* ws = (float*)d_ws;
    // persistent across whole launch:
    unsigned short* affb = (unsigned short*)ws;             // 65536 bf16 = 32768 f
    unsigned short* aswz = (unsigned short*)(ws + 65536);   // 73728 bf16 = 36864 f
    // pool/proj scratch:
    float* px1 = ws + 102400;                               // 573440 f
    float* px  = ws + 675840;                               // 573440 f
    float* PQ  = ws + 1249280;                               // 573440 f
    float* PK  = ws + 1822720;                               // 71680 f  -> end 1894400
    unsigned short* Yp  = (unsigned short*)(ws + 9539584);  // 4*8*9216*32 bf16 = 4718592 f
    // total: 14258176 floats = 57.0 MB

    aswz_kernel<<<288, 256, 0, stream>>>(con, aswz);
    pool_kernel<<<4096, 256, 0, stream>>>(x1, x, px1, px);
    proj_kernel<<<B * 72, 320, 0, stream>>>(px1, px, wq, bq, wk, bk, PQ, PK);
    aff_kernel<<<B * 32, 256, 0, stream>>>(PQ, PK, affb);
    yconv_mfma<<<768, 256, 0, stream>>>(x1, aswz, Yp);
    mix_kernel<<<1152, 256, 0, stream>>>(Yp, affb, out);
}

// Round 8
// 293.162 us; speedup vs baseline: 1.1195x; 1.1195x over previous
//
#include <hip/hip_runtime.h>
#include <hip/hip_bf16.h>

// Problem: B=8, C=256, H=W=96, c8=32, pool sizes {1,3,5,7,14} -> 280 positions.
// Restructured: out[b,o] = sum_k aff[b,o,k] * conv3x3(x_1[b], con[k])
//               psp(wq@x+bq) = wq@psp(x)+bq  (pool rows sum to 1)
// yconv as implicit-GEMM bf16 MFMA on channel-last bf16 x_1 (x2bf pass,
// L3-resident); mix as MFMA GEMM over K=32 with kc summed in the accumulator.
// proj/aff tiled to kill L2/L3 re-reads (16 outputs/block; PK in LDS).
// pool: h-bin first directly from global, then w-prefix + differences.

#define B 8
#define C 256
#define C8 32
#define H 96
#define W 96
#define HW 9216
#define NPOS 280
#define NWBIN 30
#define RPS 108   // colp stride (floats)
#define OTS 68    // mix epilogue LDS stride (floats)
#define XCH 260   // x2bf LDS channel stride (halfwords)
#define PKS 284   // aff PK LDS row stride (floats): 16B-aligned, 4-way worst

typedef __attribute__((ext_vector_type(8))) short short8;
typedef __attribute__((ext_vector_type(4))) float float4v;
typedef __attribute__((ext_vector_type(4))) unsigned short ushort4v;

static __device__ __forceinline__ unsigned short f2bf(float f) {
    unsigned u = __float_as_uint(f);
    unsigned r = (u + 0x7FFF + ((u >> 16) & 1)) >> 16;   // RNE
    return (unsigned short)r;
}
static __device__ __forceinline__ float bf2f(unsigned short h) {
    unsigned u = ((unsigned)h) << 16;
    return __uint_as_float(u);
}

// Accumulate one half-column (48 rows starting at compile-time H0, column w)
// into the 30 h-bins, reading DIRECTLY from global (coalesced across lanes).
template<int H0>
static __device__ __forceinline__ void accum_half_col(const float* __restrict__ col0,
                                                      float acc[NWBIN]) {
    const int SC[5]   = {1, 3, 5, 7, 14};
    const int WOFF[5] = {0, 1, 4, 9, 16};
    #pragma unroll
    for (int k = 0; k < NWBIN; ++k) acc[k] = 0.f;
    #pragma unroll
    for (int g = 0; g < 4; ++g) {
        float v[12];
        #pragma unroll
        for (int q = 0; q < 12; ++q) v[q] = col0[(size_t)(H0 + g * 12 + q) * 96];
        #pragma unroll
        for (int q = 0; q < 12; ++q) {
            const int h = H0 + g * 12 + q;
            #pragma unroll
            for (int si = 0; si < 5; ++si) {
                #pragma unroll
                for (int j = 0; j < SC[si]; ++j) {
                    const int st = (j * 96) / SC[si];
                    const int en = (96 * (j + 1) + SC[si] - 1) / SC[si];
                    if (h >= st && h < en) acc[WOFF[si] + j] += v[q];
                }
            }
        }
    }
}

// ---------------- pooling: [B,C,96,96] -> [B,C,280] for both x_1 and x ----
__global__ __launch_bounds__(256) void pool_kernel(const float* __restrict__ x1,
                                                   const float* __restrict__ x,
                                                   float* __restrict__ px1,
                                                   float* __restrict__ px) {
    __shared__ __align__(16) float colp[NWBIN * RPS];   // 12960 B
    const int bi = blockIdx.x;           // 0..4095
    const int which = bi >> 11;          // 0: x_1, 1: x
    const int bc = bi & 2047;
    const float* __restrict__ src = (which ? x : x1) + (size_t)bc * HW;
    float* __restrict__ dst = (which ? px : px1) + (size_t)bc * NPOS;
    const int tid = threadIdx.x;

    const int SC[5]   = {1, 3, 5, 7, 14};
    const int WOFF[5] = {0, 1, 4, 9, 16};
    const int POFF[5] = {0, 1, 10, 35, 84};

    // phase 1: h-bin accumulation into registers, straight from global
    float acc[NWBIN];
    if (tid < 96) {                              // column w=tid, h in [0,48)
        accum_half_col<0>(src + tid, acc);
    } else if (tid >= 128 && tid < 224) {        // column, h in [48,96)
        accum_half_col<48>(src + (tid - 128), acc);
    }

    // upper half publishes
    if (tid >= 128 && tid < 224) {
        const int w1 = tid - 128;
        #pragma unroll
        for (int si = 0; si < 5; ++si) {
            #pragma unroll
            for (int i = 0; i < SC[si]; ++i)
                colp[(WOFF[si] + i) * RPS + w1] = acc[WOFF[si] + i];
        }
    }
    __syncthreads();
    // combine halves + scale by 1/(h-bin width)
    if (tid < 96) {
        #pragma unroll
        for (int si = 0; si < 5; ++si) {
            #pragma unroll
            for (int i = 0; i < SC[si]; ++i) {
                const int st = (i * 96) / SC[si];
                const int en = (96 * (i + 1) + SC[si] - 1) / SC[si];
                const float inv = 1.0f / (float)(en - st);
                const int bin = WOFF[si] + i;
                colp[bin * RPS + tid] = (acc[bin] + colp[bin * RPS + tid]) * inv;
            }
        }
    }
    __syncthreads();

    // phase C: in-place prefix sum over w per h-bin (30 threads, b128)
    if (tid < NWBIN) {
        float run = 0.f;
        #pragma unroll
        for (int c = 0; c < 24; ++c) {
            float4 v = *(const float4*)&colp[tid * RPS + 4 * c];
            v.x += run; v.y += v.x; v.z += v.y; v.w += v.z;
            run = v.w;
            *(float4*)&colp[tid * RPS + 4 * c] = v;
        }
    }
    __syncthreads();

    // phase D: 280 outputs, each = w-prefix difference * 1/(w-bin width)
    for (int p = tid; p < NPOS; p += 256) {
        int si;
        if (p < 1) si = 0; else if (p < 10) si = 1; else if (p < 35) si = 2;
        else if (p < 84) si = 3; else si = 4;
        int s = SC[si];
        int loc = p - POFF[si];
        int i = loc / s;            // h-bin index
        int j = loc - i * s;        // w-bin index
        int st = (j * 96) / s;
        int en = (96 * (j + 1) + s - 1) / s;
        int binrow = WOFF[si] + i;
        float hi = colp[binrow * RPS + (en - 1)];
        float lo = (st > 0) ? colp[binrow * RPS + (st - 1)] : 0.f;
        dst[p] = (hi - lo) * (1.0f / (float)(en - st));
    }
}

// ---------------- proj v2: 16 outputs/block, weight tile in LDS -----------
// PQ = wq@px1+bq [B,256,280]; PK = wk@px+bk [B,32,280]
// grid = B * 18 (16 PQ-tiles + 2 PK-tiles per b), 320 threads.
__global__ __launch_bounds__(320) void proj_kernel(const float* __restrict__ px1,
                                                   const float* __restrict__ px,
                                                   const float* __restrict__ wq,
                                                   const float* __restrict__ bq,
                                                   const float* __restrict__ wk,
                                                   const float* __restrict__ bk,
                                                   float* __restrict__ PQ,
                                                   float* __restrict__ PK) {
    __shared__ float wt[16 * 256];   // 16 KB
    const int bi = blockIdx.x;   // B * 18
    const int b = bi / 18;
    const int r = bi % 18;
    const int tid = threadIdx.x;
    const float* src;
    const float* wm;
    const float* bias;
    float* dst;
    int o0;
    if (r < 16) {
        o0 = r * 16;
        src = px1 + (size_t)b * C * NPOS;
        wm = wq; bias = bq;
        dst = PQ + ((size_t)b * C + o0) * NPOS;
    } else {
        o0 = (r - 16) * 16;
        src = px + (size_t)b * C * NPOS;
        wm = wk; bias = bk;
        dst = PK + ((size_t)b * C8 + o0) * NPOS;
    }
    // stage 16 weight rows (coalesced; rows contiguous in o)
    for (int idx = tid; idx < 4096; idx += 320) wt[idx] = wm[o0 * C + idx];
    __syncthreads();
    if (tid >= NPOS) return;

    float acc[16];
    #pragma unroll
    for (int i = 0; i < 16; ++i) acc[i] = 0.f;
    #pragma unroll 4
    for (int c = 0; c < C; ++c) {
        float xv = src[c * NPOS + tid];          // coalesced
        #pragma unroll
        for (int i = 0; i < 16; ++i)
            acc[i] += wt[i * 256 + c] * xv;      // LDS broadcast (uniform addr)
    }
    #pragma unroll
    for (int i = 0; i < 16; ++i)
        dst[i * NPOS + tid] = acc[i] + bias[o0 + i];
}

// ---------------- aff v2: block = (b, 8 o-rows) x all 32 k -> bf16 --------
// PK[b] staged once in LDS (padded rows); PQ rows read as global float4
// broadcast (uniform across each 32-lane k-group). grid = B*32, 256 thr.
__global__ __launch_bounds__(256) void aff_kernel(const float* __restrict__ PQ,
                                                  const float* __restrict__ PK,
                                                  unsigned short* __restrict__ affb) {
    __shared__ __align__(16) float pk[C8 * PKS];   // 36352 B
    const int bi = blockIdx.x;
    const int b = bi >> 5;
    const int og = bi & 31;          // 8 o-rows per block
    const int tid = threadIdx.x;

    // stage PK[b]: 32 rows x 280 f32 = 2240 float4, coalesced
    const float* __restrict__ pkb = PK + (size_t)b * C8 * NPOS;
    for (int idx = tid; idx < 2240; idx += 256) {
        int row = idx / 70;
        int c4 = idx - row * 70;
        *(float4*)&pk[row * PKS + c4 * 4] = *(const float4*)&pkb[row * NPOS + c4 * 4];
    }
    __syncthreads();

    const int k = tid & 31;
    const int o = og * 8 + (tid >> 5);
    const float4* __restrict__ q4 = (const float4*)(PQ + ((size_t)b * C + o) * NPOS);
    const float4* __restrict__ p4 = (const float4*)&pk[k * PKS];
    float acc = 0.f;
    #pragma unroll 10
    for (int i = 0; i < NPOS / 4; ++i) {
        float4 a = q4[i];    // broadcast across k-group
        float4 c = p4[i];    // stride-PKS rows, <=4-way banks
        acc += a.x * c.x + a.y * c.y + a.z * c.z + a.w * c.w;
    }
    float s = 1.0f / (1.0f + __expf(-acc));
    affb[((size_t)b * C + o) * C8 + k] = f2bf(s);
}

// ---------------- prep: con[k,c,3,3] -> Aswz in MFMA A-fragment order ------
__global__ __launch_bounds__(256) void aswz_kernel(const float* __restrict__ con,
                                                   unsigned short* __restrict__ aswz) {
    int idx = blockIdx.x * 256 + threadIdx.x;   // 72*2*64*8 = 73728
    if (idx >= 73728) return;
    int j = idx & 7;
    int lane = (idx >> 3) & 63;
    int mt = (idx >> 9) & 1;
    int s = idx >> 10;          // 0..71
    int pos = s >> 3;
    int cg = s & 7;
    int m = lane & 15, quad = lane >> 4;
    int ko = mt * 16 + m;
    int c = cg * 32 + quad * 8 + j;
    int dy = pos / 3, dx = pos - dy * 3;
    float v = con[((ko * C + c) * 3 + dy) * 3 + dx];
    aswz[idx] = f2bf(v);
}

// ---------------- transpose x1[b,c,pix] f32 -> xbf[b,pix,c] bf16 -----------
// block = 64 px x ALL 256 ch (33.3 KB LDS). Reads 256B-coalesced f32;
// writes 512B fully-contiguous ushort4 wave stores. L3-resident both ways.
__global__ __launch_bounds__(256) void x2bf_kernel(const float* __restrict__ x1,
                                                   unsigned short* __restrict__ xbf) {
    __shared__ __align__(16) unsigned short tl[64 * XCH];   // 33280 B
    const int bi = blockIdx.x;
    const int b = bi / 144;
    const int pt = bi % 144;
    const int p0 = pt * 64;
    const int wid = threadIdx.x >> 6;
    const int lane = threadIdx.x & 63;

    #pragma unroll 8
    for (int it = 0; it < 64; ++it) {
        int ch = it * 4 + wid;
        float v = x1[((size_t)(b * C + ch)) * HW + p0 + lane];
        tl[lane * XCH + ch] = f2bf(v);
    }
    __syncthreads();
    #pragma unroll
    for (int it = 0; it < 16; ++it) {
        int pr = it * 4 + wid;  // pixel within tile
        ushort4v v = *(const ushort4v*)&tl[pr * XCH + lane * 4];
        *(ushort4v*)&xbf[((size_t)b * HW + p0 + pr) * 256 + lane * 4] = v;
    }
}

// ---------------- Y = W @ im2col(x1) via MFMA, K split over 4 blocks -------
// Output layout: Yp[kc][b][px][k] bf16 (k contiguous) for MFMA-ready mix.
__global__ __launch_bounds__(256) void yconv_mfma(const unsigned short* __restrict__ xbf,
                                                  const unsigned short* __restrict__ aswz,
                                                  unsigned short* __restrict__ Yp) {
    __shared__ unsigned short xsl[10 * 50 * 40];   // [row][col][ch pad 40] = 40000 B
    const int bi = blockIdx.x;
    const int kc = bi & 3;
    const int rest = bi >> 2;          // 0..191
    const int tilex = rest & 1;
    const int tiley = (rest >> 1) % 12;
    const int b = rest / 24;
    const int tid = threadIdx.x;
    const int wid = tid >> 6;
    const int lane = tid & 63;
    const int n = lane & 15, quad = lane >> 4;

    float4v acc[2][6];
    #pragma unroll
    for (int mt = 0; mt < 2; ++mt)
        #pragma unroll
        for (int t = 0; t < 6; ++t)
            acc[mt][t] = (float4v){0.f, 0.f, 0.f, 0.f};

    int baseb[6];
    #pragma unroll
    for (int t = 0; t < 6; ++t) {
        int tt = wid * 6 + t;
        int rt = tt / 3;
        int xb = (tt % 3) * 16;
        baseb[t] = (rt * 50 + xb + n) * 40 + quad * 8;
    }

    for (int ci = 0; ci < 2; ++ci) {
        const int cg = kc * 2 + ci;
        __syncthreads();
        // stage X slab: 10 rows x 50 cols x 32 ch bf16, pure uint4 copies
        for (int task = tid; task < 2000; task += 256) {
            int pix = task >> 2;       // 0..499
            int cq = task & 3;
            int r = pix / 50;
            int col = pix - r * 50;
            int gy = tiley * 8 + r - 1;
            int gx = tilex * 48 + col - 1;
            uint4 v = make_uint4(0u, 0u, 0u, 0u);
            if ((unsigned)gy < 96u && (unsigned)gx < 96u)
                v = *(const uint4*)&xbf[((size_t)b * HW + gy * 96 + gx) * 256 + cg * 32 + cq * 8];
            *(uint4*)&xsl[(r * 50 + col) * 40 + cq * 8] = v;
        }
        // A-fragments straight from global (L2-hot, 18 x 16B per lane)
        short8 af[9][2];
        #pragma unroll
        for (int pos = 0; pos < 9; ++pos)
            #pragma unroll
            for (int mt = 0; mt < 2; ++mt)
                af[pos][mt] = *(const short8*)&aswz[((((pos * 8 + cg) * 2) + mt) * 64 + lane) * 8];
        __syncthreads();

        #pragma unroll
        for (int pos = 0; pos < 9; ++pos) {
            const int dy = pos / 3, dx = pos - (pos / 3) * 3;
            const int d = (dy * 50 + dx) * 40;
            #pragma unroll
            for (int t = 0; t < 6; ++t) {
                short8 bf = *(const short8*)&xsl[baseb[t] + d];
                acc[0][t] = __builtin_amdgcn_mfma_f32_16x16x32_bf16(af[pos][0], bf, acc[0][t], 0, 0, 0);
                acc[1][t] = __builtin_amdgcn_mfma_f32_16x16x32_bf16(af[pos][1], bf, acc[1][t], 0, 0, 0);
            }
        }
    }

    // store partial: D col=lane&15 -> pixel n, row=quad*4+reg -> k_out.
    #pragma unroll
    for (int mt = 0; mt < 2; ++mt) {
        #pragma unroll
        for (int t = 0; t < 6; ++t) {
            int tt = wid * 6 + t;
            int rt = tt / 3;
            int xb = (tt % 3) * 16;
            int gy = tiley * 8 + rt;
            int gx = tilex * 48 + xb + n;
            ushort4v v;
            #pragma unroll
            for (int reg = 0; reg < 4; ++reg) v[reg] = f2bf(acc[mt][t][reg]);
            *(ushort4v*)&Yp[((((size_t)kc * B + b) * HW + gy * 96 + gx)) * C8 + mt * 16 + quad * 4] = v;
        }
    }
}

// ---------------- mix: out[b,o,px] = sum_k aff[b,o,k] * sum_kc Yp ----------
__global__ __launch_bounds__(256) void mix_kernel(const unsigned short* __restrict__ Yp,
                                                  const unsigned short* __restrict__ affb,
                                                  float* __restrict__ out) {
    __shared__ float ot[128 * OTS];   // 34816 B
    const int bi = blockIdx.x;   // 1152
    const int b = bi / 144;
    const int pg = bi % 144;
    const int wid = threadIdx.x >> 6;
    const int lane = threadIdx.x & 63;
    const int n = lane & 15, quad = lane >> 4;
    const int px0 = pg * 64 + wid * 16;   // this wave's 16-px column tile

    // B-frags, one per kc: B[k=quad*8+j][n(px)] ; wave reads 1KB contiguous
    short8 y0 = *(const short8*)&Yp[(((size_t)0 * B + b) * HW + px0 + n) * C8 + quad * 8];
    short8 y1 = *(const short8*)&Yp[(((size_t)1 * B + b) * HW + px0 + n) * C8 + quad * 8];
    short8 y2 = *(const short8*)&Yp[(((size_t)2 * B + b) * HW + px0 + n) * C8 + quad * 8];
    short8 y3 = *(const short8*)&Yp[(((size_t)3 * B + b) * HW + px0 + n) * C8 + quad * 8];

    float4v acc[16];
    #pragma unroll
    for (int mt = 0; mt < 16; ++mt) acc[mt] = (float4v){0.f, 0.f, 0.f, 0.f};

    #pragma unroll
    for (int mt = 0; mt < 16; ++mt) {
        const short8 a = *(const short8*)&affb[((size_t)b * C + mt * 16 + n) * C8 + quad * 8];
        acc[mt] = __builtin_amdgcn_mfma_f32_16x16x32_bf16(a, y0, acc[mt], 0, 0, 0);
        acc[mt] = __builtin_amdgcn_mfma_f32_16x16x32_bf16(a, y1, acc[mt], 0, 0, 0);
        acc[mt] = __builtin_amdgcn_mfma_f32_16x16x32_bf16(a, y2, acc[mt], 0, 0, 0);
        acc[mt] = __builtin_amdgcn_mfma_f32_16x16x32_bf16(a, y3, acc[mt], 0, 0, 0);
    }

    // epilogue: two halves of 128 o-rows through LDS -> contiguous 256B stores
    #pragma unroll
    for (int half = 0; half < 2; ++half) {
        __syncthreads();
        #pragma unroll
        for (int mt = 0; mt < 8; ++mt) {
            #pragma unroll
            for (int reg = 0; reg < 4; ++reg) {
                ot[(mt * 16 + quad * 4 + reg) * OTS + wid * 16 + n] = acc[half * 8 + mt][reg];
            }
        }
        __syncthreads();
        #pragma unroll
        for (int i = 0; i < 32; ++i) {
            int o = wid * 32 + i;          // local o within half
            out[((size_t)b * C + half * 128 + o) * HW + pg * 64 + lane] = ot[o * OTS + lane];
        }
    }
}

extern "C" void kernel_launch(void* const* d_in, const int* in_sizes, int n_in,
                              void* d_out, int out_size, void* d_ws, size_t ws_size,
                              hipStream_t stream) {
    const float* x1  = (const float*)d_in[0];
    const float* x   = (const float*)d_in[1];
    const float* wq  = (const float*)d_in[2];
    const float* bq  = (const float*)d_in[3];
    const float* wk  = (const float*)d_in[4];
    const float* bk  = (const float*)d_in[5];
    const float* con = (const float*)d_in[6];
    float* out = (float*)d_out;

    float* ws = (float*)d_ws;
    // persistent across whole launch:
    unsigned short* affb = (unsigned short*)ws;             // 65536 bf16 = 32768 f
    unsigned short* aswz = (unsigned short*)(ws + 65536);   // 73728 bf16 = 36864 f
    // pool/proj scratch (dead after aff_kernel):
    float* px1 = ws + 102400;                               // 573440 f
    float* px  = ws + 675840;                               // 573440 f
    float* PQ  = ws + 1249280;                              // 573440 f
    float* PK  = ws + 1822720;                              // 71680 f  -> end 1894400
    // xbf ALIASES the pool/proj scratch (x2bf launches after aff_kernel):
    unsigned short* xbf = (unsigned short*)(ws + 102400);   // 8*9216*256 bf16 = 9437184 f
    unsigned short* Yp  = (unsigned short*)(ws + 9539584);  // 4*8*9216*32 bf16 = 4718592 f
    // total: 14258176 floats = 57.0 MB

    aswz_kernel<<<288, 256, 0, stream>>>(con, aswz);
    pool_kernel<<<4096, 256, 0, stream>>>(x1, x, px1, px);
    proj_kernel<<<B * 18, 320, 0, stream>>>(px1, px, wq, bq, wk, bk, PQ, PK);
    aff_kernel<<<B * 32, 256, 0, stream>>>(PQ, PK, affb);
    x2bf_kernel<<<1152, 256, 0, stream>>>(x1, xbf);         // after aff: aliasing safe
    yconv_mfma<<<768, 256, 0, stream>>>(xbf, aswz, Yp);
    mix_kernel<<<1152, 256, 0, stream>>>(Yp, affb, out);
}

// Round 10
// 269.561 us; speedup vs baseline: 1.2175x; 1.0876x over previous
//
#include <hip/hip_runtime.h>
#include <hip/hip_bf16.h>

// Problem: B=8, C=256, H=W=96, c8=32, pool sizes {1,3,5,7,14} -> 280 positions.
// Restructured: out[b,o] = sum_k aff[b,o,k] * conv3x3(x_1[b], con[k])
//               psp(wq@x+bq) = wq@psp(x)+bq  (pool rows sum to 1)
// FULL MFMA pipeline: pool emits bf16 [b][p][c]; proj & aff are MFMA GEMMs;
// yconv implicit-GEMM; mix MFMA GEMM over K=32 (kc summed in accumulator).

#define B 8
#define C 256
#define C8 32
#define H 96
#define W 96
#define HW 9216
#define NPOS 280
#define NP 288    // NPOS padded to 9 K-steps of 32
#define NWBIN 30
#define RPS 108   // colp stride (floats)
#define OTS 68    // mix epilogue LDS stride (floats)
#define XCH 260   // x2bf LDS channel stride (halfwords)
#define PJS 304   // proj epilogue LDS row stride (halfwords)

typedef __attribute__((ext_vector_type(8))) short short8;
typedef __attribute__((ext_vector_type(4))) float float4v;
typedef __attribute__((ext_vector_type(4))) unsigned short ushort4v;

static __device__ __forceinline__ unsigned short f2bf(float f) {
    unsigned u = __float_as_uint(f);
    unsigned r = (u + 0x7FFF + ((u >> 16) & 1)) >> 16;   // RNE
    return (unsigned short)r;
}
static __device__ __forceinline__ float bf2f(unsigned short h) {
    unsigned u = ((unsigned)h) << 16;
    return __uint_as_float(u);
}

// Accumulate one half-column (48 rows starting at compile-time H0, column w)
// into the 30 h-bins, reading DIRECTLY from global (coalesced across lanes).
template<int H0>
static __device__ __forceinline__ void accum_half_col(const float* __restrict__ col0,
                                                      float acc[NWBIN]) {
    const int SC[5]   = {1, 3, 5, 7, 14};
    const int WOFF[5] = {0, 1, 4, 9, 16};
    #pragma unroll
    for (int k = 0; k < NWBIN; ++k) acc[k] = 0.f;
    #pragma unroll
    for (int g = 0; g < 4; ++g) {
        float v[12];
        #pragma unroll
        for (int q = 0; q < 12; ++q) v[q] = col0[(size_t)(H0 + g * 12 + q) * 96];
        #pragma unroll
        for (int q = 0; q < 12; ++q) {
            const int h = H0 + g * 12 + q;
            #pragma unroll
            for (int si = 0; si < 5; ++si) {
                #pragma unroll
                for (int j = 0; j < SC[si]; ++j) {
                    const int st = (j * 96) / SC[si];
                    const int en = (96 * (j + 1) + SC[si] - 1) / SC[si];
                    if (h >= st && h < en) acc[WOFF[si] + j] += v[q];
                }
            }
        }
    }
}

// ---------------- pooling: [B,C,96,96] -> bf16 [B,288,C] for x_1 and x ----
// h-bin first directly from global, w-prefix + differences; output written
// transposed ([p][c], c contiguous) bf16, pad rows p in [280,288) zeroed.
__global__ __launch_bounds__(256) void pool_kernel(const float* __restrict__ x1,
                                                   const float* __restrict__ x,
                                                   unsigned short* __restrict__ px1t,
                                                   unsigned short* __restrict__ pxt) {
    __shared__ __align__(16) float colp[NWBIN * RPS];   // 12960 B
    const int bi = blockIdx.x;           // 0..4095
    const int which = bi >> 11;          // 0: x_1, 1: x
    const int bc = bi & 2047;            // b*C + c
    const float* __restrict__ src = (which ? x : x1) + (size_t)bc * HW;
    const int b = bc >> 8;
    const int c = bc & 255;
    unsigned short* __restrict__ dstT = (which ? pxt : px1t) + ((size_t)b * NP) * C + c;
    const int tid = threadIdx.x;

    const int SC[5]   = {1, 3, 5, 7, 14};
    const int WOFF[5] = {0, 1, 4, 9, 16};
    const int POFF[5] = {0, 1, 10, 35, 84};

    // phase 1: h-bin accumulation into registers, straight from global
    float acc[NWBIN];
    if (tid < 96) {                              // column w=tid, h in [0,48)
        accum_half_col<0>(src + tid, acc);
    } else if (tid >= 128 && tid < 224) {        // column, h in [48,96)
        accum_half_col<48>(src + (tid - 128), acc);
    }

    // upper half publishes
    if (tid >= 128 && tid < 224) {
        const int w1 = tid - 128;
        #pragma unroll
        for (int si = 0; si < 5; ++si) {
            #pragma unroll
            for (int i = 0; i < SC[si]; ++i)
                colp[(WOFF[si] + i) * RPS + w1] = acc[WOFF[si] + i];
        }
    }
    __syncthreads();
    // combine halves + scale by 1/(h-bin width)
    if (tid < 96) {
        #pragma unroll
        for (int si = 0; si < 5; ++si) {
            #pragma unroll
            for (int i = 0; i < SC[si]; ++i) {
                const int st = (i * 96) / SC[si];
                const int en = (96 * (i + 1) + SC[si] - 1) / SC[si];
                const float inv = 1.0f / (float)(en - st);
                const int bin = WOFF[si] + i;
                colp[bin * RPS + tid] = (acc[bin] + colp[bin * RPS + tid]) * inv;
            }
        }
    }
    __syncthreads();

    // phase C: in-place prefix sum over w per h-bin (30 threads, b128)
    if (tid < NWBIN) {
        float run = 0.f;
        #pragma unroll
        for (int cc = 0; cc < 24; ++cc) {
            float4 v = *(const float4*)&colp[tid * RPS + 4 * cc];
            v.x += run; v.y += v.x; v.z += v.y; v.w += v.z;
            run = v.w;
            *(float4*)&colp[tid * RPS + 4 * cc] = v;
        }
    }
    __syncthreads();

    // phase D: 280 outputs -> bf16 transposed store; zero the 8 pad rows
    for (int p = tid; p < NPOS; p += 256) {
        int si;
        if (p < 1) si = 0; else if (p < 10) si = 1; else if (p < 35) si = 2;
        else if (p < 84) si = 3; else si = 4;
        int s = SC[si];
        int loc = p - POFF[si];
        int i = loc / s;            // h-bin index
        int j = loc - i * s;        // w-bin index
        int st = (j * 96) / s;
        int en = (96 * (j + 1) + s - 1) / s;
        int binrow = WOFF[si] + i;
        float hi = colp[binrow * RPS + (en - 1)];
        float lo = (st > 0) ? colp[binrow * RPS + (st - 1)] : 0.f;
        dstT[(size_t)p * C] = f2bf((hi - lo) * (1.0f / (float)(en - st)));
    }
    if (tid < NP - NPOS) dstT[(size_t)(NPOS + tid) * C] = 0;
}

// ---------------- proj MFMA: PQb = wq@px1t+bq ; PKb = wk@pxt+bk  (bf16) ----
// M=o (16 rows/block), N=p (288, 18 ntiles), K=c (256, 8 ksteps).
// Output [row][p] bf16 with p contiguous (aff fragment layout), p>=280 -> 0.
// grid = B*18 (16 PQ mtiles + 2 PK mtiles), 256 thr.
__global__ __launch_bounds__(256) void proj_mfma(const unsigned short* __restrict__ px1t,
                                                 const unsigned short* __restrict__ pxt,
                                                 const float* __restrict__ wq,
                                                 const float* __restrict__ bq,
                                                 const float* __restrict__ wk,
                                                 const float* __restrict__ bk,
                                                 unsigned short* __restrict__ PQb,
                                                 unsigned short* __restrict__ PKb) {
    __shared__ __align__(16) unsigned short lds[16 * PJS];   // 9728 B
    const int bi = blockIdx.x;
    const int b = bi / 18;
    const int mt = bi % 18;
    const int tid = threadIdx.x;
    const int wid = tid >> 6;
    const int lane = tid & 63;
    const int n = lane & 15, quad = lane >> 4;
    const bool isQ = (mt < 16);
    const int row0 = isQ ? mt * 16 : (mt - 16) * 16;
    const float* __restrict__ wm = isQ ? wq : wk;
    const float* __restrict__ bias = isQ ? bq : bk;
    const unsigned short* __restrict__ src = (isQ ? px1t : pxt) + (size_t)b * NP * C;

    // A-frags: A[m=row][k=c], cast f32 weights -> bf16 (8 ksteps)
    short8 af[8];
    #pragma unroll
    for (int ks = 0; ks < 8; ++ks) {
        const float* wr = &wm[(row0 + n) * C + ks * 32 + quad * 8];
        short8 a;
        #pragma unroll
        for (int j = 0; j < 8; ++j) a[j] = (short)f2bf(wr[j]);
        af[ks] = a;
    }

    float4v acc[5];
    #pragma unroll
    for (int t = 0; t < 5; ++t) acc[t] = (float4v){0.f, 0.f, 0.f, 0.f};

    #pragma unroll
    for (int t = 0; t < 5; ++t) {
        const int nt = t * 4 + wid;
        if (nt < 18) {
            #pragma unroll
            for (int ks = 0; ks < 8; ++ks) {
                // B-frag: B[k=c][n=p] from src[p][c] (c contiguous)
                short8 bf = *(const short8*)&src[(size_t)(nt * 16 + n) * C + ks * 32 + quad * 8];
                acc[t] = __builtin_amdgcn_mfma_f32_16x16x32_bf16(af[ks], bf, acc[t], 0, 0, 0);
            }
        }
    }

    // epilogue: D[row=quad*4+reg][col=p] + bias -> LDS [row][p] -> coalesced
    #pragma unroll
    for (int t = 0; t < 5; ++t) {
        const int nt = t * 4 + wid;
        if (nt < 18) {
            #pragma unroll
            for (int reg = 0; reg < 4; ++reg) {
                float v = acc[t][reg] + bias[row0 + quad * 4 + reg];
                lds[(quad * 4 + reg) * PJS + nt * 16 + n] = f2bf(v);
            }
        }
    }
    __syncthreads();
    unsigned short* __restrict__ dstb = isQ ? PQb + ((size_t)b * C + row0) * NP
                                            : PKb + ((size_t)b * C8 + row0) * NP;
    for (int idx = tid; idx < 16 * 144; idx += 256) {
        int r = idx / 144;
        int c2 = idx - r * 144;
        unsigned int v = 0u;
        if (c2 < 140) v = *(const unsigned int*)&lds[r * PJS + c2 * 2];
        ((unsigned int*)&dstb[(size_t)r * NP])[c2] = v;   // p>=280 zeroed
    }
}

// ---------------- aff MFMA: aff^T[k8][o] = PK @ PQ^T, sigmoid -> bf16 ------
// M=k8 (32, 2 mtiles), N=o (64/block), K=p (288, 9 ksteps).
// D rows = k8 (4 consecutive per reg) -> ushort4 stores in mix's affb layout.
// grid = B*4, 256 thr.
__global__ __launch_bounds__(256) void aff_mfma(const unsigned short* __restrict__ PQb,
                                                const unsigned short* __restrict__ PKb,
                                                unsigned short* __restrict__ affb) {
    const int bi = blockIdx.x;
    const int b = bi >> 2;
    const int og = bi & 3;
    const int tid = threadIdx.x;
    const int wid = tid >> 6;
    const int lane = tid & 63;
    const int n = lane & 15, quad = lane >> 4;
    const int o = og * 64 + wid * 16 + n;

    float4v acc[2];
    acc[0] = (float4v){0.f, 0.f, 0.f, 0.f};
    acc[1] = (float4v){0.f, 0.f, 0.f, 0.f};

    #pragma unroll
    for (int ks = 0; ks < 9; ++ks) {
        // B-frag: B[k=p][n=o] from PQb[o][p] (p contiguous)
        short8 bfr = *(const short8*)&PQb[((size_t)b * C + o) * NP + ks * 32 + quad * 8];
        #pragma unroll
        for (int mt = 0; mt < 2; ++mt) {
            // A-frag: A[m=k8][k=p] from PKb[k8][p] (p contiguous)
            short8 a = *(const short8*)&PKb[((size_t)b * C8 + mt * 16 + n) * NP + ks * 32 + quad * 8];
            acc[mt] = __builtin_amdgcn_mfma_f32_16x16x32_bf16(a, bfr, acc[mt], 0, 0, 0);
        }
    }

    #pragma unroll
    for (int mt = 0; mt < 2; ++mt) {
        ushort4v v;
        #pragma unroll
        for (int reg = 0; reg < 4; ++reg) {
            float s = 1.0f / (1.0f + __expf(-acc[mt][reg]));
            v[reg] = f2bf(s);
        }
        *(ushort4v*)&affb[((size_t)b * C + o) * C8 + mt * 16 + quad * 4] = v;
    }
}

// ---------------- prep: con[k,c,3,3] -> Aswz in MFMA A-fragment order ------
__global__ __launch_bounds__(256) void aswz_kernel(const float* __restrict__ con,
                                                   unsigned short* __restrict__ aswz) {
    int idx = blockIdx.x * 256 + threadIdx.x;   // 72*2*64*8 = 73728
    if (idx >= 73728) return;
    int j = idx & 7;
    int lane = (idx >> 3) & 63;
    int mt = (idx >> 9) & 1;
    int s = idx >> 10;          // 0..71
    int pos = s >> 3;
    int cg = s & 7;
    int m = lane & 15, quad = lane >> 4;
    int ko = mt * 16 + m;
    int c = cg * 32 + quad * 8 + j;
    int dy = pos / 3, dx = pos - dy * 3;
    float v = con[((ko * C + c) * 3 + dy) * 3 + dx];
    aswz[idx] = f2bf(v);
}

// ---------------- transpose x1[b,c,pix] f32 -> xbf[b,pix,c] bf16 -----------
__global__ __launch_bounds__(256) void x2bf_kernel(const float* __restrict__ x1,
                                                   unsigned short* __restrict__ xbf) {
    __shared__ __align__(16) unsigned short tl[64 * XCH];   // 33280 B
    const int bi = blockIdx.x;
    const int b = bi / 144;
    const int pt = bi % 144;
    const int p0 = pt * 64;
    const int wid = threadIdx.x >> 6;
    const int lane = threadIdx.x & 63;

    #pragma unroll 8
    for (int it = 0; it < 64; ++it) {
        int ch = it * 4 + wid;
        float v = x1[((size_t)(b * C + ch)) * HW + p0 + lane];
        tl[lane * XCH + ch] = f2bf(v);
    }
    __syncthreads();
    #pragma unroll
    for (int it = 0; it < 16; ++it) {
        int pr = it * 4 + wid;  // pixel within tile
        ushort4v v = *(const ushort4v*)&tl[pr * XCH + lane * 4];
        *(ushort4v*)&xbf[((size_t)b * HW + p0 + pr) * 256 + lane * 4] = v;
    }
}

// ---------------- Y = W @ im2col(x1) via MFMA, K split over 4 blocks -------
__global__ __launch_bounds__(256) void yconv_mfma(const unsigned short* __restrict__ xbf,
                                                  const unsigned short* __restrict__ aswz,
                                                  unsigned short* __restrict__ Yp) {
    __shared__ unsigned short xsl[10 * 50 * 40];   // [row][col][ch pad 40] = 40000 B
    const int bi = blockIdx.x;
    const int kc = bi & 3;
    const int rest = bi >> 2;          // 0..191
    const int tilex = rest & 1;
    const int tiley = (rest >> 1) % 12;
    const int b = rest / 24;
    const int tid = threadIdx.x;
    const int wid = tid >> 6;
    const int lane = tid & 63;
    const int n = lane & 15, quad = lane >> 4;

    float4v acc[2][6];
    #pragma unroll
    for (int mt = 0; mt < 2; ++mt)
        #pragma unroll
        for (int t = 0; t < 6; ++t)
            acc[mt][t] = (float4v){0.f, 0.f, 0.f, 0.f};

    int baseb[6];
    #pragma unroll
    for (int t = 0; t < 6; ++t) {
        int tt = wid * 6 + t;
        int rt = tt / 3;
        int xb = (tt % 3) * 16;
        baseb[t] = (rt * 50 + xb + n) * 40 + quad * 8;
    }

    for (int ci = 0; ci < 2; ++ci) {
        const int cg = kc * 2 + ci;
        __syncthreads();
        for (int task = tid; task < 2000; task += 256) {
            int pix = task >> 2;       // 0..499
            int cq = task & 3;
            int r = pix / 50;
            int col = pix - r * 50;
            int gy = tiley * 8 + r - 1;
            int gx = tilex * 48 + col - 1;
            uint4 v = make_uint4(0u, 0u, 0u, 0u);
            if ((unsigned)gy < 96u && (unsigned)gx < 96u)
                v = *(const uint4*)&xbf[((size_t)b * HW + gy * 96 + gx) * 256 + cg * 32 + cq * 8];
            *(uint4*)&xsl[(r * 50 + col) * 40 + cq * 8] = v;
        }
        short8 af[9][2];
        #pragma unroll
        for (int pos = 0; pos < 9; ++pos)
            #pragma unroll
            for (int mt = 0; mt < 2; ++mt)
                af[pos][mt] = *(const short8*)&aswz[((((pos * 8 + cg) * 2) + mt) * 64 + lane) * 8];
        __syncthreads();

        #pragma unroll
        for (int pos = 0; pos < 9; ++pos) {
            const int dy = pos / 3, dx = pos - (pos / 3) * 3;
            const int d = (dy * 50 + dx) * 40;
            #pragma unroll
            for (int t = 0; t < 6; ++t) {
                short8 bf = *(const short8*)&xsl[baseb[t] + d];
                acc[0][t] = __builtin_amdgcn_mfma_f32_16x16x32_bf16(af[pos][0], bf, acc[0][t], 0, 0, 0);
                acc[1][t] = __builtin_amdgcn_mfma_f32_16x16x32_bf16(af[pos][1], bf, acc[1][t], 0, 0, 0);
            }
        }
    }

    #pragma unroll
    for (int mt = 0; mt < 2; ++mt) {
        #pragma unroll
        for (int t = 0; t < 6; ++t) {
            int tt = wid * 6 + t;
            int rt = tt / 3;
            int xb = (tt % 3) * 16;
            int gy = tiley * 8 + rt;
            int gx = tilex * 48 + xb + n;
            ushort4v v;
            #pragma unroll
            for (int reg = 0; reg < 4; ++reg) v[reg] = f2bf(acc[mt][t][reg]);
            *(ushort4v*)&Yp[((((size_t)kc * B + b) * HW + gy * 96 + gx)) * C8 + mt * 16 + quad * 4] = v;
        }
    }
}

// ---------------- mix: out[b,o,px] = sum_k aff[b,o,k] * sum_kc Yp ----------
__global__ __launch_bounds__(256) void mix_kernel(const unsigned short* __restrict__ Yp,
                                                  const unsigned short* __restrict__ affb,
                                                  float* __restrict__ out) {
    __shared__ float ot[128 * OTS];   // 34816 B
    const int bi = blockIdx.x;   // 1152
    const int b = bi / 144;
    const int pg = bi % 144;
    const int wid = threadIdx.x >> 6;
    const int lane = threadIdx.x & 63;
    const int n = lane & 15, quad = lane >> 4;
    const int px0 = pg * 64 + wid * 16;

    short8 y0 = *(const short8*)&Yp[(((size_t)0 * B + b) * HW + px0 + n) * C8 + quad * 8];
    short8 y1 = *(const short8*)&Yp[(((size_t)1 * B + b) * HW + px0 + n) * C8 + quad * 8];
    short8 y2 = *(const short8*)&Yp[(((size_t)2 * B + b) * HW + px0 + n) * C8 + quad * 8];
    short8 y3 = *(const short8*)&Yp[(((size_t)3 * B + b) * HW + px0 + n) * C8 + quad * 8];

    float4v acc[16];
    #pragma unroll
    for (int mt = 0; mt < 16; ++mt) acc[mt] = (float4v){0.f, 0.f, 0.f, 0.f};

    #pragma unroll
    for (int mt = 0; mt < 16; ++mt) {
        const short8 a = *(const short8*)&affb[((size_t)b * C + mt * 16 + n) * C8 + quad * 8];
        acc[mt] = __builtin_amdgcn_mfma_f32_16x16x32_bf16(a, y0, acc[mt], 0, 0, 0);
        acc[mt] = __builtin_amdgcn_mfma_f32_16x16x32_bf16(a, y1, acc[mt], 0, 0, 0);
        acc[mt] = __builtin_amdgcn_mfma_f32_16x16x32_bf16(a, y2, acc[mt], 0, 0, 0);
        acc[mt] = __builtin_amdgcn_mfma_f32_16x16x32_bf16(a, y3, acc[mt], 0, 0, 0);
    }

    #pragma unroll
    for (int half = 0; half < 2; ++half) {
        __syncthreads();
        #pragma unroll
        for (int mt = 0; mt < 8; ++mt) {
            #pragma unroll
            for (int reg = 0; reg < 4; ++reg) {
                ot[(mt * 16 + quad * 4 + reg) * OTS + wid * 16 + n] = acc[half * 8 + mt][reg];
            }
        }
        __syncthreads();
        #pragma unroll
        for (int i = 0; i < 32; ++i) {
            int o = wid * 32 + i;
            out[((size_t)b * C + half * 128 + o) * HW + pg * 64 + lane] = ot[o * OTS + lane];
        }
    }
}

extern "C" void kernel_launch(void* const* d_in, const int* in_sizes, int n_in,
                              void* d_out, int out_size, void* d_ws, size_t ws_size,
                              hipStream_t stream) {
    const float* x1  = (const float*)d_in[0];
    const float* x   = (const float*)d_in[1];
    const float* wq  = (const float*)d_in[2];
    const float* bq  = (const float*)d_in[3];
    const float* wk  = (const float*)d_in[4];
    const float* bk  = (const float*)d_in[5];
    const float* con = (const float*)d_in[6];
    float* out = (float*)d_out;

    float* ws = (float*)d_ws;
    // persistent across whole launch:
    unsigned short* affb = (unsigned short*)ws;              // 65536 bf16 = 32768 f
    unsigned short* aswz = (unsigned short*)(ws + 65536);    // 73728 bf16 = 36864 f
    // pool/proj scratch (dead after aff_mfma):
    unsigned short* px1t = (unsigned short*)(ws + 102400);   // 8*288*256 bf16 = 294912 f
    unsigned short* pxt  = (unsigned short*)(ws + 397312);   // 294912 f
    unsigned short* PQb  = (unsigned short*)(ws + 692224);   // 8*256*288 bf16 = 294912 f
    unsigned short* PKb  = (unsigned short*)(ws + 987136);   // 8*32*288 bf16 = 36864 f -> end 1024000
    // xbf ALIASES the scratch (x2bf launches after aff_mfma):
    unsigned short* xbf = (unsigned short*)(ws + 102400);    // 8*9216*256 bf16 = 4718592 f
    unsigned short* Yp  = (unsigned short*)(ws + 9539584);   // 4*8*9216*32 bf16 = 2359296 f
    // total: 57.0 MB (unchanged)

    aswz_kernel<<<288, 256, 0, stream>>>(con, aswz);
    pool_kernel<<<4096, 256, 0, stream>>>(x1, x, px1t, pxt);
    proj_mfma<<<B * 18, 256, 0, stream>>>(px1t, pxt, wq, bq, wk, bk, PQb, PKb);
    aff_mfma<<<B * 4, 256, 0, stream>>>(PQb, PKb, affb);
    x2bf_kernel<<<1152, 256, 0, stream>>>(x1, xbf);          // after aff: aliasing safe
    yconv_mfma<<<768, 256, 0, stream>>>(xbf, aswz, Yp);
    mix_kernel<<<1152, 256, 0, stream>>>(Yp, affb, out);
}

// Round 11
// 259.116 us; speedup vs baseline: 1.2666x; 1.0403x over previous
//
#include <hip/hip_runtime.h>
#include <hip/hip_bf16.h>

// Problem: B=8, C=256, H=W=96, c8=32, pool sizes {1,3,5,7,14} -> 280 positions.
// Restructured: out[b,o] = sum_k aff[b,o,k] * conv3x3(x_1[b], con[k])
//               psp(wq@x+bq) = wq@psp(x)+bq  (pool rows sum to 1)
// FULL MFMA pipeline in 4 launches:
//   L1 fusedA = pool + x2bf + aswz (independent, block-range fused)
//   L2 proj_mfma ; L3 fusedC = aff_mfma + yconv ; L4 mix

#define B 8
#define C 256
#define C8 32
#define H 96
#define W 96
#define HW 9216
#define NPOS 280
#define NP 288    // NPOS padded to 9 K-steps of 32
#define NWBIN 30
#define RPS 108   // colp stride (floats)
#define OTS 68    // mix epilogue LDS stride (floats)
#define XCH 260   // x2bf LDS channel stride (halfwords)
#define PJS 304   // proj epilogue LDS row stride (halfwords)

typedef __attribute__((ext_vector_type(8))) short short8;
typedef __attribute__((ext_vector_type(4))) float float4v;
typedef __attribute__((ext_vector_type(4))) unsigned short ushort4v;

static __device__ __forceinline__ unsigned short f2bf(float f) {
    unsigned u = __float_as_uint(f);
    unsigned r = (u + 0x7FFF + ((u >> 16) & 1)) >> 16;   // RNE
    return (unsigned short)r;
}

// Accumulate one half-column (48 rows starting at compile-time H0, column w)
// into the 30 h-bins, reading DIRECTLY from global (coalesced across lanes).
template<int H0>
static __device__ __forceinline__ void accum_half_col(const float* __restrict__ col0,
                                                      float acc[NWBIN]) {
    const int SC[5]   = {1, 3, 5, 7, 14};
    const int WOFF[5] = {0, 1, 4, 9, 16};
    #pragma unroll
    for (int k = 0; k < NWBIN; ++k) acc[k] = 0.f;
    #pragma unroll
    for (int g = 0; g < 4; ++g) {
        float v[12];
        #pragma unroll
        for (int q = 0; q < 12; ++q) v[q] = col0[(size_t)(H0 + g * 12 + q) * 96];
        #pragma unroll
        for (int q = 0; q < 12; ++q) {
            const int h = H0 + g * 12 + q;
            #pragma unroll
            for (int si = 0; si < 5; ++si) {
                #pragma unroll
                for (int j = 0; j < SC[si]; ++j) {
                    const int st = (j * 96) / SC[si];
                    const int en = (96 * (j + 1) + SC[si] - 1) / SC[si];
                    if (h >= st && h < en) acc[WOFF[si] + j] += v[q];
                }
            }
        }
    }
}

// ---------------- pool body: [B,C,96,96] -> bf16 [B,288,C] -----------------
static __device__ __forceinline__ void pool_body(int bi, const float* __restrict__ x1,
                                                 const float* __restrict__ x,
                                                 unsigned short* __restrict__ px1t,
                                                 unsigned short* __restrict__ pxt,
                                                 float* colp) {
    const int which = bi >> 11;          // 0: x_1, 1: x
    const int bc = bi & 2047;            // b*C + c
    const float* __restrict__ src = (which ? x : x1) + (size_t)bc * HW;
    const int b = bc >> 8;
    const int c = bc & 255;
    unsigned short* __restrict__ dstT = (which ? pxt : px1t) + ((size_t)b * NP) * C + c;
    const int tid = threadIdx.x;

    const int SC[5]   = {1, 3, 5, 7, 14};
    const int WOFF[5] = {0, 1, 4, 9, 16};
    const int POFF[5] = {0, 1, 10, 35, 84};

    float acc[NWBIN];
    if (tid < 96) {                              // column w=tid, h in [0,48)
        accum_half_col<0>(src + tid, acc);
    } else if (tid >= 128 && tid < 224) {        // column, h in [48,96)
        accum_half_col<48>(src + (tid - 128), acc);
    }

    if (tid >= 128 && tid < 224) {
        const int w1 = tid - 128;
        #pragma unroll
        for (int si = 0; si < 5; ++si) {
            #pragma unroll
            for (int i = 0; i < SC[si]; ++i)
                colp[(WOFF[si] + i) * RPS + w1] = acc[WOFF[si] + i];
        }
    }
    __syncthreads();
    if (tid < 96) {
        #pragma unroll
        for (int si = 0; si < 5; ++si) {
            #pragma unroll
            for (int i = 0; i < SC[si]; ++i) {
                const int st = (i * 96) / SC[si];
                const int en = (96 * (i + 1) + SC[si] - 1) / SC[si];
                const float inv = 1.0f / (float)(en - st);
                const int bin = WOFF[si] + i;
                colp[bin * RPS + tid] = (acc[bin] + colp[bin * RPS + tid]) * inv;
            }
        }
    }
    __syncthreads();

    if (tid < NWBIN) {
        float run = 0.f;
        #pragma unroll
        for (int cc = 0; cc < 24; ++cc) {
            float4 v = *(const float4*)&colp[tid * RPS + 4 * cc];
            v.x += run; v.y += v.x; v.z += v.y; v.w += v.z;
            run = v.w;
            *(float4*)&colp[tid * RPS + 4 * cc] = v;
        }
    }
    __syncthreads();

    for (int p = tid; p < NPOS; p += 256) {
        int si;
        if (p < 1) si = 0; else if (p < 10) si = 1; else if (p < 35) si = 2;
        else if (p < 84) si = 3; else si = 4;
        int s = SC[si];
        int loc = p - POFF[si];
        int i = loc / s;            // h-bin index
        int j = loc - i * s;        // w-bin index
        int st = (j * 96) / s;
        int en = (96 * (j + 1) + s - 1) / s;
        int binrow = WOFF[si] + i;
        float hi = colp[binrow * RPS + (en - 1)];
        float lo = (st > 0) ? colp[binrow * RPS + (st - 1)] : 0.f;
        dstT[(size_t)p * C] = f2bf((hi - lo) * (1.0f / (float)(en - st)));
    }
    if (tid < NP - NPOS) dstT[(size_t)(NPOS + tid) * C] = 0;
}

// ---------------- x2bf body: x1[b,c,pix] f32 -> xbf[b,pix,c] bf16 ----------
static __device__ __forceinline__ void x2bf_body(int bi, const float* __restrict__ x1,
                                                 unsigned short* __restrict__ xbf,
                                                 unsigned short* tl) {
    const int b = bi / 144;
    const int pt = bi % 144;
    const int p0 = pt * 64;
    const int wid = threadIdx.x >> 6;
    const int lane = threadIdx.x & 63;

    #pragma unroll 8
    for (int it = 0; it < 64; ++it) {
        int ch = it * 4 + wid;
        float v = x1[((size_t)(b * C + ch)) * HW + p0 + lane];
        tl[lane * XCH + ch] = f2bf(v);
    }
    __syncthreads();
    #pragma unroll
    for (int it = 0; it < 16; ++it) {
        int pr = it * 4 + wid;  // pixel within tile
        ushort4v v = *(const ushort4v*)&tl[pr * XCH + lane * 4];
        *(ushort4v*)&xbf[((size_t)b * HW + p0 + pr) * 256 + lane * 4] = v;
    }
}

// ---------------- aswz body: con[k,c,3,3] -> MFMA A-fragment order ---------
static __device__ __forceinline__ void aswz_body(int idx, const float* __restrict__ con,
                                                 unsigned short* __restrict__ aswz) {
    if (idx >= 73728) return;
    int j = idx & 7;
    int lane = (idx >> 3) & 63;
    int mt = (idx >> 9) & 1;
    int s = idx >> 10;          // 0..71
    int pos = s >> 3;
    int cg = s & 7;
    int m = lane & 15, quad = lane >> 4;
    int ko = mt * 16 + m;
    int c = cg * 32 + quad * 8 + j;
    int dy = pos / 3, dx = pos - dy * 3;
    float v = con[((ko * C + c) * 3 + dy) * 3 + dx];
    aswz[idx] = f2bf(v);
}

// ---------------- L1: fusedA = pool + x2bf + aswz --------------------------
// grid = 4096 + 1152 + 288 = 5536 blocks, 256 thr. All branches independent.
__global__ __launch_bounds__(256) void fusedA(const float* __restrict__ x1,
                                              const float* __restrict__ x,
                                              const float* __restrict__ con,
                                              unsigned short* __restrict__ px1t,
                                              unsigned short* __restrict__ pxt,
                                              unsigned short* __restrict__ xbf,
                                              unsigned short* __restrict__ aswz) {
    __shared__ __align__(16) unsigned char smem[64 * XCH * 2];   // 33280 B (max of bodies)
    const int bi = blockIdx.x;
    if (bi < 4096) {
        pool_body(bi, x1, x, px1t, pxt, (float*)smem);
    } else if (bi < 5248) {
        x2bf_body(bi - 4096, x1, xbf, (unsigned short*)smem);
    } else {
        aswz_body((bi - 5248) * 256 + threadIdx.x, con, aswz);
    }
}

// ---------------- L2: proj MFMA: PQb = wq@px1t+bq ; PKb = wk@pxt+bk --------
// M=o (16 rows/block), N=p (288, 18 ntiles), K=c (256, 8 ksteps).
// Output [row][p] bf16 with p contiguous (aff fragment layout), p>=280 -> 0.
__global__ __launch_bounds__(256) void proj_mfma(const unsigned short* __restrict__ px1t,
                                                 const unsigned short* __restrict__ pxt,
                                                 const float* __restrict__ wq,
                                                 const float* __restrict__ bq,
                                                 const float* __restrict__ wk,
                                                 const float* __restrict__ bk,
                                                 unsigned short* __restrict__ PQb,
                                                 unsigned short* __restrict__ PKb) {
    __shared__ __align__(16) unsigned short lds[16 * PJS];   // 9728 B
    const int bi = blockIdx.x;
    const int b = bi / 18;
    const int mt = bi % 18;
    const int tid = threadIdx.x;
    const int wid = tid >> 6;
    const int lane = tid & 63;
    const int n = lane & 15, quad = lane >> 4;
    const bool isQ = (mt < 16);
    const int row0 = isQ ? mt * 16 : (mt - 16) * 16;
    const float* __restrict__ wm = isQ ? wq : wk;
    const float* __restrict__ bias = isQ ? bq : bk;
    const unsigned short* __restrict__ src = (isQ ? px1t : pxt) + (size_t)b * NP * C;

    short8 af[8];
    #pragma unroll
    for (int ks = 0; ks < 8; ++ks) {
        const float* wr = &wm[(row0 + n) * C + ks * 32 + quad * 8];
        short8 a;
        #pragma unroll
        for (int j = 0; j < 8; ++j) a[j] = (short)f2bf(wr[j]);
        af[ks] = a;
    }

    float4v acc[5];
    #pragma unroll
    for (int t = 0; t < 5; ++t) acc[t] = (float4v){0.f, 0.f, 0.f, 0.f};

    #pragma unroll
    for (int t = 0; t < 5; ++t) {
        const int nt = t * 4 + wid;
        if (nt < 18) {
            #pragma unroll
            for (int ks = 0; ks < 8; ++ks) {
                short8 bf = *(const short8*)&src[(size_t)(nt * 16 + n) * C + ks * 32 + quad * 8];
                acc[t] = __builtin_amdgcn_mfma_f32_16x16x32_bf16(af[ks], bf, acc[t], 0, 0, 0);
            }
        }
    }

    #pragma unroll
    for (int t = 0; t < 5; ++t) {
        const int nt = t * 4 + wid;
        if (nt < 18) {
            #pragma unroll
            for (int reg = 0; reg < 4; ++reg) {
                float v = acc[t][reg] + bias[row0 + quad * 4 + reg];
                lds[(quad * 4 + reg) * PJS + nt * 16 + n] = f2bf(v);
            }
        }
    }
    __syncthreads();
    unsigned short* __restrict__ dstb = isQ ? PQb + ((size_t)b * C + row0) * NP
                                            : PKb + ((size_t)b * C8 + row0) * NP;
    for (int idx = tid; idx < 16 * 144; idx += 256) {
        int r = idx / 144;
        int c2 = idx - r * 144;
        unsigned int v = 0u;
        if (c2 < 140) v = *(const unsigned int*)&lds[r * PJS + c2 * 2];
        ((unsigned int*)&dstb[(size_t)r * NP])[c2] = v;   // p>=280 zeroed
    }
}

// ---------------- aff body: aff^T = PK @ PQ^T, sigmoid -> bf16 -------------
static __device__ __forceinline__ void aff_body(int bi, const unsigned short* __restrict__ PQb,
                                                const unsigned short* __restrict__ PKb,
                                                unsigned short* __restrict__ affb) {
    const int b = bi >> 2;
    const int og = bi & 3;
    const int tid = threadIdx.x;
    const int wid = tid >> 6;
    const int lane = tid & 63;
    const int n = lane & 15, quad = lane >> 4;
    const int o = og * 64 + wid * 16 + n;

    float4v acc[2];
    acc[0] = (float4v){0.f, 0.f, 0.f, 0.f};
    acc[1] = (float4v){0.f, 0.f, 0.f, 0.f};

    #pragma unroll
    for (int ks = 0; ks < 9; ++ks) {
        short8 bfr = *(const short8*)&PQb[((size_t)b * C + o) * NP + ks * 32 + quad * 8];
        #pragma unroll
        for (int mt = 0; mt < 2; ++mt) {
            short8 a = *(const short8*)&PKb[((size_t)b * C8 + mt * 16 + n) * NP + ks * 32 + quad * 8];
            acc[mt] = __builtin_amdgcn_mfma_f32_16x16x32_bf16(a, bfr, acc[mt], 0, 0, 0);
        }
    }

    #pragma unroll
    for (int mt = 0; mt < 2; ++mt) {
        ushort4v v;
        #pragma unroll
        for (int reg = 0; reg < 4; ++reg) {
            float s = 1.0f / (1.0f + __expf(-acc[mt][reg]));
            v[reg] = f2bf(s);
        }
        *(ushort4v*)&affb[((size_t)b * C + o) * C8 + mt * 16 + quad * 4] = v;
    }
}

// ---------------- yconv body: Y = W @ im2col(x1), K split over 4 -----------
static __device__ __forceinline__ void yconv_body(int bi, const unsigned short* __restrict__ xbf,
                                                  const unsigned short* __restrict__ aswz,
                                                  unsigned short* __restrict__ Yp,
                                                  unsigned short* xsl) {
    const int kc = bi & 3;
    const int rest = bi >> 2;          // 0..191
    const int tilex = rest & 1;
    const int tiley = (rest >> 1) % 12;
    const int b = rest / 24;
    const int tid = threadIdx.x;
    const int wid = tid >> 6;
    const int lane = tid & 63;
    const int n = lane & 15, quad = lane >> 4;

    float4v acc[2][6];
    #pragma unroll
    for (int mt = 0; mt < 2; ++mt)
        #pragma unroll
        for (int t = 0; t < 6; ++t)
            acc[mt][t] = (float4v){0.f, 0.f, 0.f, 0.f};

    int baseb[6];
    #pragma unroll
    for (int t = 0; t < 6; ++t) {
        int tt = wid * 6 + t;
        int rt = tt / 3;
        int xb = (tt % 3) * 16;
        baseb[t] = (rt * 50 + xb + n) * 40 + quad * 8;
    }

    for (int ci = 0; ci < 2; ++ci) {
        const int cg = kc * 2 + ci;
        __syncthreads();
        for (int task = tid; task < 2000; task += 256) {
            int pix = task >> 2;       // 0..499
            int cq = task & 3;
            int r = pix / 50;
            int col = pix - r * 50;
            int gy = tiley * 8 + r - 1;
            int gx = tilex * 48 + col - 1;
            uint4 v = make_uint4(0u, 0u, 0u, 0u);
            if ((unsigned)gy < 96u && (unsigned)gx < 96u)
                v = *(const uint4*)&xbf[((size_t)b * HW + gy * 96 + gx) * 256 + cg * 32 + cq * 8];
            *(uint4*)&xsl[(r * 50 + col) * 40 + cq * 8] = v;
        }
        short8 af[9][2];
        #pragma unroll
        for (int pos = 0; pos < 9; ++pos)
            #pragma unroll
            for (int mt = 0; mt < 2; ++mt)
                af[pos][mt] = *(const short8*)&aswz[((((pos * 8 + cg) * 2) + mt) * 64 + lane) * 8];
        __syncthreads();

        #pragma unroll
        for (int pos = 0; pos < 9; ++pos) {
            const int dy = pos / 3, dx = pos - (pos / 3) * 3;
            const int d = (dy * 50 + dx) * 40;
            #pragma unroll
            for (int t = 0; t < 6; ++t) {
                short8 bf = *(const short8*)&xsl[baseb[t] + d];
                acc[0][t] = __builtin_amdgcn_mfma_f32_16x16x32_bf16(af[pos][0], bf, acc[0][t], 0, 0, 0);
                acc[1][t] = __builtin_amdgcn_mfma_f32_16x16x32_bf16(af[pos][1], bf, acc[1][t], 0, 0, 0);
            }
        }
    }

    #pragma unroll
    for (int mt = 0; mt < 2; ++mt) {
        #pragma unroll
        for (int t = 0; t < 6; ++t) {
            int tt = wid * 6 + t;
            int rt = tt / 3;
            int xb = (tt % 3) * 16;
            int gy = tiley * 8 + rt;
            int gx = tilex * 48 + xb + n;
            ushort4v v;
            #pragma unroll
            for (int reg = 0; reg < 4; ++reg) v[reg] = f2bf(acc[mt][t][reg]);
            *(ushort4v*)&Yp[((((size_t)kc * B + b) * HW + gy * 96 + gx)) * C8 + mt * 16 + quad * 4] = v;
        }
    }
}

// ---------------- L3: fusedC = aff_mfma (first 32) + yconv (768) -----------
__global__ __launch_bounds__(256) void fusedC(const unsigned short* __restrict__ PQb,
                                              const unsigned short* __restrict__ PKb,
                                              unsigned short* __restrict__ affb,
                                              const unsigned short* __restrict__ xbf,
                                              const unsigned short* __restrict__ aswz,
                                              unsigned short* __restrict__ Yp) {
    __shared__ __align__(16) unsigned short xsl[10 * 50 * 40];   // 40000 B
    const int bi = blockIdx.x;
    if (bi < 32) {
        aff_body(bi, PQb, PKb, affb);
    } else {
        yconv_body(bi - 32, xbf, aswz, Yp, xsl);
    }
}

// ---------------- L4: mix: out[b,o,px] = sum_k aff[b,o,k] * sum_kc Yp ------
__global__ __launch_bounds__(256) void mix_kernel(const unsigned short* __restrict__ Yp,
                                                  const unsigned short* __restrict__ affb,
                                                  float* __restrict__ out) {
    __shared__ float ot[128 * OTS];   // 34816 B
    const int bi = blockIdx.x;   // 1152
    const int b = bi / 144;
    const int pg = bi % 144;
    const int wid = threadIdx.x >> 6;
    const int lane = threadIdx.x & 63;
    const int n = lane & 15, quad = lane >> 4;
    const int px0 = pg * 64 + wid * 16;

    short8 y0 = *(const short8*)&Yp[(((size_t)0 * B + b) * HW + px0 + n) * C8 + quad * 8];
    short8 y1 = *(const short8*)&Yp[(((size_t)1 * B + b) * HW + px0 + n) * C8 + quad * 8];
    short8 y2 = *(const short8*)&Yp[(((size_t)2 * B + b) * HW + px0 + n) * C8 + quad * 8];
    short8 y3 = *(const short8*)&Yp[(((size_t)3 * B + b) * HW + px0 + n) * C8 + quad * 8];

    float4v acc[16];
    #pragma unroll
    for (int mt = 0; mt < 16; ++mt) acc[mt] = (float4v){0.f, 0.f, 0.f, 0.f};

    #pragma unroll
    for (int mt = 0; mt < 16; ++mt) {
        const short8 a = *(const short8*)&affb[((size_t)b * C + mt * 16 + n) * C8 + quad * 8];
        acc[mt] = __builtin_amdgcn_mfma_f32_16x16x32_bf16(a, y0, acc[mt], 0, 0, 0);
        acc[mt] = __builtin_amdgcn_mfma_f32_16x16x32_bf16(a, y1, acc[mt], 0, 0, 0);
        acc[mt] = __builtin_amdgcn_mfma_f32_16x16x32_bf16(a, y2, acc[mt], 0, 0, 0);
        acc[mt] = __builtin_amdgcn_mfma_f32_16x16x32_bf16(a, y3, acc[mt], 0, 0, 0);
    }

    #pragma unroll
    for (int half = 0; half < 2; ++half) {
        __syncthreads();
        #pragma unroll
        for (int mt = 0; mt < 8; ++mt) {
            #pragma unroll
            for (int reg = 0; reg < 4; ++reg) {
                ot[(mt * 16 + quad * 4 + reg) * OTS + wid * 16 + n] = acc[half * 8 + mt][reg];
            }
        }
        __syncthreads();
        #pragma unroll
        for (int i = 0; i < 32; ++i) {
            int o = wid * 32 + i;
            out[((size_t)b * C + half * 128 + o) * HW + pg * 64 + lane] = ot[o * OTS + lane];
        }
    }
}

extern "C" void kernel_launch(void* const* d_in, const int* in_sizes, int n_in,
                              void* d_out, int out_size, void* d_ws, size_t ws_size,
                              hipStream_t stream) {
    const float* x1  = (const float*)d_in[0];
    const float* x   = (const float*)d_in[1];
    const float* wq  = (const float*)d_in[2];
    const float* bq  = (const float*)d_in[3];
    const float* wk  = (const float*)d_in[4];
    const float* bk  = (const float*)d_in[5];
    const float* con = (const float*)d_in[6];
    float* out = (float*)d_out;

    float* ws = (float*)d_ws;
    // de-aliased map (pool & x2bf run concurrently in L1):
    unsigned short* affb = (unsigned short*)ws;               // [0,32768)
    unsigned short* aswz = (unsigned short*)(ws + 32768);     // [32768,69632)
    unsigned short* PQb  = (unsigned short*)(ws + 69632);     // [69632,364544)   L2->L3
    unsigned short* PKb  = (unsigned short*)(ws + 364544);    // [364544,401408)  L2->L3
    unsigned short* xbf  = (unsigned short*)(ws + 401408);    // [401408,9838592) L1->L3
    unsigned short* px1t = (unsigned short*)(ws + 9838592);   // [9838592,10133504) L1->L2
    unsigned short* pxt  = (unsigned short*)(ws + 10133504);  // [10133504,10428416) L1->L2
    unsigned short* Yp   = (unsigned short*)(ws + 9838592);   // [9838592,14557184) L3->L4
    // Yp aliases px1t/pxt (dead after L2). total: 14557184 f = 58.2 MB

    fusedA<<<5536, 256, 0, stream>>>(x1, x, con, px1t, pxt, xbf, aswz);
    proj_mfma<<<B * 18, 256, 0, stream>>>(px1t, pxt, wq, bq, wk, bk, PQb, PKb);
    fusedC<<<32 + 768, 256, 0, stream>>>(PQb, PKb, affb, xbf, aswz, Yp);
    mix_kernel<<<1152, 256, 0, stream>>>(Yp, affb, out);
}